// Round 4
// baseline (1272.586 us; speedup 1.0000x reference)
//
#include <hip/hip_runtime.h>
#include <hip/hip_bf16.h>

#define D_IN 256
#define DM   1024
#define HD   2048
#define NE   8
#define NTOK 16384

typedef __attribute__((ext_vector_type(8))) short short8;
typedef __attribute__((ext_vector_type(4))) float f32x4;
typedef unsigned int uint;

// ---- meta layout (uint indices) ----
#define MT_TOFF1 0      // [64][8]   per-tile chunk-relative offsets, L1 lists
#define MT_TOFF2 512    // [64][16]  per-tile offsets, L2 (slot,e) lists
#define MT_CNT1  1536   // [8][8]
#define MT_P1    1600   // [8][8]    roundup128(cnt1)
#define MT_OFF1  1664   // [8][8]    t1 row offset per expert (chunk-relative)
#define MT_CNT2  1728   // [8][16]
#define MT_PCNT2 1856   // [8][16]
#define MT_TOTAL 1984

__device__ inline ushort f2bf(float v){
  __hip_bfloat16 b = __float2bfloat16(v);
  return *reinterpret_cast<ushort*>(&b);
}
__device__ inline float bf2f(ushort u){
  __hip_bfloat16 b = *reinterpret_cast<__hip_bfloat16*>(&u);
  return __bfloat162float(b);
}

// gelu tanh-approx via exact identity 0.5*(1+tanh(u)) = sigmoid(2u):
// gelu(x) = x / (1 + exp(-2u)), u = 0.79788456*(x + 0.044715 x^3)
// (replaces libm tanhf; error ~1e-7, invisible under bf16 output rounding)
__device__ inline float gelu_fast(float x){
  float u = 0.7978845608028654f * x * (1.0f + 0.044715f*x*x);
  return x / (1.0f + __expf(-2.0f*u));
}

__device__ inline void gload16(const void* g, void* l){
  __builtin_amdgcn_global_load_lds(
      (const __attribute__((address_space(1))) void*)g,
      (__attribute__((address_space(3))) void*)l, 16, 0, 0);
}

// ---------- transpose [R][C] f32 -> [C][R] bf16 (per expert, blockIdx.z) ----------
__global__ __launch_bounds__(256) void transpose_bf16_kernel(
    const float* __restrict__ src, ushort* __restrict__ dst, int R, int C)
{
  __shared__ float tile[32][33];
  int e = blockIdx.z;
  src += (size_t)e*R*C; dst += (size_t)e*R*C;
  int c0 = blockIdx.x*32, r0 = blockIdx.y*32;
  int tx = threadIdx.x & 31, ty = threadIdx.x >> 5;
  #pragma unroll
  for (int rr = ty; rr < 32; rr += 8)
    tile[rr][tx] = src[(size_t)(r0+rr)*C + c0+tx];
  __syncthreads();
  #pragma unroll
  for (int rr = ty; rr < 32; rr += 8)
    dst[(size_t)(c0+rr)*R + r0+tx] = f2bf(tile[tx][rr]);
}

// ---------- split x[N][256] f32 -> xs3[N][768] bf16 (hi|mid|lo 256-blocks) ----------
__global__ __launch_bounds__(256) void split_x_kernel(
    const float* __restrict__ x, ushort* __restrict__ xs3)
{
  int g = blockIdx.x*256 + threadIdx.x;     // one thread = 4 consecutive floats
  int e0 = g*4;
  int row = e0 >> 8, col = e0 & 255;
  f32x4 v = *(const f32x4*)(x + (size_t)row*D_IN + col);
  ushort4 hi, mi, lo;
  #pragma unroll
  for (int i=0;i<4;++i){
    float f = v[i];
    ushort h = f2bf(f);       float fh = bf2f(h);
    ushort m = f2bf(f - fh);  float fm = bf2f(m);
    ushort l = f2bf(f - fh - fm);
    ((ushort*)&hi)[i]=h; ((ushort*)&mi)[i]=m; ((ushort*)&lo)[i]=l;
  }
  ushort* base = xs3 + (size_t)row*768 + col;
  *(ushort4*)(base)       = hi;
  *(ushort4*)(base + 256) = mi;
  *(ushort4*)(base + 512) = lo;
}

// ---------- transpose+split w_in[256][1024] f32 -> wt3[1024][768] bf16 ----------
__global__ __launch_bounds__(256) void transpose_split3_kernel(
    const float* __restrict__ src, ushort* __restrict__ dst)
{
  __shared__ float tile[32][33];
  int c0 = blockIdx.x*32, r0 = blockIdx.y*32;
  int tx = threadIdx.x & 31, ty = threadIdx.x >> 5;
  #pragma unroll
  for (int rr = ty; rr < 32; rr += 8)
    tile[rr][tx] = src[(size_t)(r0+rr)*DM + c0+tx];
  __syncthreads();
  #pragma unroll
  for (int rr = ty; rr < 32; rr += 8){
    float f = tile[tx][rr];   // src[r0+tx][c0+rr]
    ushort h = f2bf(f);       float fh = bf2f(h);
    ushort m = f2bf(f - fh);  float fm = bf2f(m);
    ushort l = f2bf(f - fh - fm);
    ushort* d = dst + (size_t)(c0+rr)*768 + r0 + tx;
    d[0]   = h;
    d[256] = m;
    d[512] = l;
  }
}

// ---------- w_gate[1024][8] -> wgt[8][1024] ----------
__global__ __launch_bounds__(256) void wgate_t_kernel(
    const float* __restrict__ w_gate, float* __restrict__ wgt)
{
  int e = blockIdx.x;
  for (int j = threadIdx.x; j < DM; j += 256)
    wgt[(size_t)e*DM + j] = w_gate[(size_t)j*NE + e];
}

// ---------- router GEMM: y = x @ w_in + b_in via bf16x3 (6 terms, K=6*256) ----------
__global__ __launch_bounds__(256) void gemm_router(
    const ushort* __restrict__ A,    // [NTOK][768]
    const ushort* __restrict__ BT,   // [DM][768]
    const float* __restrict__ b_in,
    float* __restrict__ y)           // [NTOK][DM]
{
  __shared__ ushort As[128*32];
  __shared__ ushort Bs[128*32];
  const int tid = threadIdx.x;
  const int w = tid>>6, l = tid&63;
  const int wm = w>>1, wn = w&1;
  const int bm0 = blockIdx.y*128, bn0 = blockIdx.x*128;
  const int lr = l&15, lk = l>>4;
  const int rsub = l>>2, csub = (l&3)*8;

  const ushort* ag[2]; const ushort* bg[2];
  ushort* al[2]; ushort* bl[2];
  #pragma unroll
  for (int i=0;i<2;++i){
    int ra = bm0 + w*32 + i*16 + rsub;
    int rb = bn0 + w*32 + i*16 + rsub;
    ag[i] = A  + (size_t)ra*768 + csub;
    bg[i] = BT + (size_t)rb*768 + csub;
    al[i] = (ushort*)As + (w*32 + i*16)*32;
    bl[i] = (ushort*)Bs + (w*32 + i*16)*32;
  }

  f32x4 zero = {0.f,0.f,0.f,0.f};
  f32x4 acc[4][4];
  #pragma unroll
  for (int i=0;i<4;++i){
    #pragma unroll
    for (int j=0;j<4;++j) acc[i][j]=zero;
  }

  const int pq[6][2] = {{0,0},{256,0},{0,256},{256,256},{512,0},{0,512}};
  for (int t=0;t<6;++t){
    int pOff = pq[t][0], qOff = pq[t][1];
    for (int kt=0; kt<256; kt+=32){
      #pragma unroll
      for (int i=0;i<2;++i){
        gload16(ag[i]+pOff+kt, al[i]);
        gload16(bg[i]+qOff+kt, bl[i]);
      }
      __syncthreads();
      short8 af[4], bf[4];
      #pragma unroll
      for (int i=0;i<4;++i) af[i] = *(const short8*)(As + (wm*64 + i*16 + lr)*32 + lk*8);
      #pragma unroll
      for (int j=0;j<4;++j) bf[j] = *(const short8*)(Bs + (wn*64 + j*16 + lr)*32 + lk*8);
      #pragma unroll
      for (int i=0;i<4;++i){
        #pragma unroll
        for (int j=0;j<4;++j)
          acc[i][j] = __builtin_amdgcn_mfma_f32_16x16x32_bf16(af[i], bf[j], acc[i][j], 0, 0, 0);
      }
      __syncthreads();
    }
  }

  #pragma unroll
  for (int i=0;i<4;++i){
    #pragma unroll
    for (int j=0;j<4;++j){
      int n = bn0 + wn*64 + j*16 + lr;
      float bn_ = b_in[n];
      #pragma unroll
      for (int r=0;r<4;++r){
        int m = bm0 + wm*64 + i*16 + lk*4 + r;
        y[(size_t)m*DM + n] = acc[i][j][r] + bn_;
      }
    }
  }
}

// ---------- LN + logits + softmax top2 (wave per token), in-place on y ----------
__device__ inline double wredd(double v){
  #pragma unroll
  for (int o=32;o>0;o>>=1) v += __shfl_xor(v, o, 64);
  return v;
}

__global__ __launch_bounds__(256) void ln_router_kernel(
    const float* __restrict__ g_in, const float* __restrict__ beta_in,
    const float* __restrict__ wgt,  // [8][1024]
    ushort* __restrict__ hbf, float* __restrict__ resid,  // resid doubles as y
    float* __restrict__ gates, int* __restrict__ selmask)
{
  int tok = blockIdx.x*4 + (threadIdx.x>>6);
  int l = threadIdx.x & 63;
  float* row = resid + (size_t)tok*DM;
  float u[16];
  double s=0.0, q=0.0;
  #pragma unroll
  for (int r=0;r<16;++r){ u[r]=row[l+64*r]; s+=u[r]; q+=(double)u[r]*u[r]; }
  s = wredd(s); q = wredd(q);
  double mean = s*(1.0/1024.0);
  double var  = q*(1.0/1024.0) - mean*mean;
  double rstd = 1.0/sqrt(var + 1e-5);

  double lg[NE];
  #pragma unroll
  for (int e=0;e<NE;++e) lg[e]=0.0;
  float hv[16];
  #pragma unroll
  for (int r=0;r<16;++r){
    int j = l + 64*r;
    double v = ((double)u[r]-mean)*rstd*(double)g_in[j] + (double)beta_in[j];
    hv[r] = (float)v;
    #pragma unroll
    for (int e=0;e<NE;++e) lg[e] += v*(double)wgt[(size_t)e*DM + j];
  }
  #pragma unroll
  for (int r=0;r<16;++r){
    int j = l + 64*r;
    row[j] = hv[r];
    hbf[(size_t)tok*DM + j] = f2bf(hv[r]);
  }
  #pragma unroll
  for (int e=0;e<NE;++e) lg[e] = wredd(lg[e]);

  if (l==0){
    double mx = lg[0];
    #pragma unroll
    for (int e=1;e<NE;++e) mx = lg[e]>mx ? lg[e] : mx;
    double p[NE]; double sum=0.0;
    #pragma unroll
    for (int e=0;e<NE;++e){ p[e]=exp(lg[e]-mx); sum+=p[e]; }
    #pragma unroll
    for (int e=0;e<NE;++e) p[e]/=sum;
    int i1=0;
    for (int e=1;e<NE;++e) if (p[e]>p[i1]) i1=e;
    int i2=-1;
    for (int e=0;e<NE;++e){ if (e==i1) continue; if (i2<0 || p[e]>p[i2]) i2=e; }
    double denom = p[i1]+p[i2]+1e-9;
    float g[NE];
    #pragma unroll
    for (int e=0;e<NE;++e) g[e]=0.f;
    g[i1]=(float)(p[i1]/denom);
    g[i2]=(float)(p[i2]/denom);
    #pragma unroll
    for (int e=0;e<NE;++e) gates[(size_t)tok*NE+e]=g[e];
    selmask[tok] = (1<<i1)|(1<<i2);
  }
}

// ---------- builders: deterministic per-(chunk,expert) token lists ----------
__global__ __launch_bounds__(256) void builder_count(
    const int* __restrict__ selmask, uint* __restrict__ bc1, uint* __restrict__ bc2)
{
  __shared__ uint c1[8], c2s[16];
  int b = blockIdx.x, tid = threadIdx.x;
  if (tid<8) c1[tid]=0;
  if (tid<16) c2s[tid]=0;
  __syncthreads();
  int m = selmask[b*256+tid];
  int ea = __ffs(m)-1, eb = 31-__clz(m);
  atomicAdd(&c1[ea],1u); atomicAdd(&c1[eb],1u);
  atomicAdd(&c2s[ea],1u); atomicAdd(&c2s[8+eb],1u);
  __syncthreads();
  if (tid<8) bc1[b*8+tid]=c1[tid];
  if (tid<16) bc2[b*16+tid]=c2s[tid];
}

__global__ __launch_bounds__(256) void builder_scan(
    const uint* __restrict__ bc1, const uint* __restrict__ bc2,
    uint* __restrict__ meta, int nch, int TPC)
{
  int tid = threadIdx.x;
  int c = tid/24, k = tid%24;
  if (c < nch){
    if (k < 8){
      uint run=0;
      for (int b=c*TPC; b<(c+1)*TPC; ++b){ meta[MT_TOFF1 + b*8 + k] = run; run += bc1[b*8+k]; }
      meta[MT_CNT1 + c*8 + k] = run;
    } else {
      int k2 = k-8;
      uint run=0;
      for (int b=c*TPC; b<(c+1)*TPC; ++b){ meta[MT_TOFF2 + b*16 + k2] = run; run += bc2[b*16+k2]; }
      meta[MT_CNT2 + c*16 + k2] = run;
      meta[MT_PCNT2 + c*16 + k2] = ((run + 127u)/128u)*128u;
    }
  }
  __syncthreads();
  if (tid < nch){
    uint off=0;
    for (int e=0;e<8;++e){
      uint cn = meta[MT_CNT1 + tid*8 + e];
      uint p = ((cn+127u)/128u)*128u;
      meta[MT_P1 + tid*8 + e] = p;
      meta[MT_OFF1 + tid*8 + e] = off;
      off += p;
    }
  }
}

__device__ inline int exclscan256(int v, int* sc, int tid){
  sc[tid]=v; __syncthreads();
  #pragma unroll
  for (int o=1;o<256;o<<=1){
    int x = (tid>=o) ? sc[tid-o] : 0;
    __syncthreads();
    sc[tid]+=x;
    __syncthreads();
  }
  int incl = sc[tid]; __syncthreads();
  return incl - v;
}

__global__ __launch_bounds__(256) void builder_fill(
    const int* __restrict__ selmask, const uint* __restrict__ meta,
    int* __restrict__ ids1, int* __restrict__ g2row, int* __restrict__ g2tok,
    int CH)
{
  __shared__ int sc[256];
  int b = blockIdx.x, tid = threadIdx.x;
  int t = b*256 + tid;
  int c = t / CH;
  int m = selmask[t];
  int ea = __ffs(m)-1, eb = 31-__clz(m);
  int ja=0, jb=0;
  for (int e=0;e<8;++e){
    int r0 = exclscan256((ea==e)?1:0, sc, tid);
    if (ea==e) ja = r0;
    int r1 = exclscan256((eb==e)?1:0, sc, tid);
    if (eb==e) jb = r1;
  }
  {
    uint j    = meta[MT_TOFF2 + b*16 + ea] + (uint)ja;
    uint pos1 = j;
    uint row  = meta[MT_OFF1 + c*8 + ea] + pos1;
    ids1[(c*8+ea)*CH + pos1] = t;
    g2row[((c*2+0)*8+ea)*CH + j] = (int)row;
    g2tok[((c*2+0)*8+ea)*CH + j] = t;
  }
  {
    uint j    = meta[MT_TOFF2 + b*16 + 8 + eb] + (uint)jb;
    uint pos1 = meta[MT_CNT2 + c*16 + eb] + j;
    uint row  = meta[MT_OFF1 + c*8 + eb] + pos1;
    ids1[(c*8+eb)*CH + pos1] = t;
    g2row[((c*2+1)*8+eb)*CH + j] = (int)row;
    g2tok[((c*2+1)*8+eb)*CH + j] = t;
  }
}

// ---------- sparse gather-GEMM, m97 structure + expert->XCD affinity ----------
// 1-D grid, bid decode: e = bid & 7 (=> expert pinned to one XCD via round-robin
// bid->XCD), then bm fastest within expert for B-tile L2 temporal reuse.
// Each XCD's 4 MiB L2 holds exactly its expert's 4 MiB B panel.
template<int EPI>
__global__ __launch_bounds__(256) void gemm_sparse(
    const ushort* __restrict__ Abase,
    const ushort* __restrict__ BT,      // [E][N][K]
    const int*   __restrict__ rows,
    const int*   __restrict__ toks,
    const uint*  __restrict__ pcnt,
    const uint*  __restrict__ cnt,
    const uint*  __restrict__ off1,
    const float* __restrict__ bias,
    const float* __restrict__ gates,
    ushort* __restrict__ t1,
    float*  __restrict__ resid,
    int K, int N, int CH)
{
  int bid = blockIdx.x;
  const int e = bid & 7;
  bid >>= 3;
  const int NBM = CH >> 7;
  const int bm0 = (bid % NBM) * 128;
  if ((uint)bm0 >= pcnt[e]) return;
  const int bn0 = (bid / NBM) * 128;

  __shared__ ushort As[128*32];
  __shared__ ushort Bs[128*32];
  const int tid = threadIdx.x;
  const int w = tid>>6, l = tid&63;
  const int wm = w>>1, wn = w&1;
  const int lr = l&15, lk = l>>4;
  const int rsub = l>>2, csub = (l&3)*8;

  const ushort* ag[2]; const ushort* bg[2];
  ushort* al[2]; ushort* bl[2];
  #pragma unroll
  for (int i=0;i<2;++i){
    int ra = w*32 + i*16 + rsub;
    int id = rows[e*CH + bm0 + ra];
    ag[i] = Abase + (size_t)id*K + csub;
    int rb = bn0 + w*32 + i*16 + rsub;
    bg[i] = BT + (size_t)e*N*K + (size_t)rb*K + csub;
    al[i] = (ushort*)As + (w*32 + i*16)*32;
    bl[i] = (ushort*)Bs + (w*32 + i*16)*32;
  }

  f32x4 zero = {0.f,0.f,0.f,0.f};
  f32x4 acc[4][4];
  #pragma unroll
  for (int i=0;i<4;++i){
    #pragma unroll
    for (int j=0;j<4;++j) acc[i][j]=zero;
  }

  for (int kt = 0; kt < K; kt += 32) {
    #pragma unroll
    for (int i=0;i<2;++i){
      gload16(ag[i]+kt, al[i]);
      gload16(bg[i]+kt, bl[i]);
    }
    __syncthreads();
    short8 af[4], bf[4];
    #pragma unroll
    for (int i=0;i<4;++i) af[i] = *(const short8*)(As + (wm*64 + i*16 + lr)*32 + lk*8);
    #pragma unroll
    for (int j=0;j<4;++j) bf[j] = *(const short8*)(Bs + (wn*64 + j*16 + lr)*32 + lk*8);
    #pragma unroll
    for (int i=0;i<4;++i){
      #pragma unroll
      for (int j=0;j<4;++j)
        acc[i][j] = __builtin_amdgcn_mfma_f32_16x16x32_bf16(af[i], bf[j], acc[i][j], 0, 0, 0);
    }
    __syncthreads();
  }

  #pragma unroll
  for (int i=0;i<4;++i){
    #pragma unroll
    for (int j=0;j<4;++j){
      int n = bn0 + wn*64 + j*16 + lr;
      float bn_ = bias[(size_t)e*N + n];
      #pragma unroll
      for (int r=0;r<4;++r){
        int mloc = wm*64 + i*16 + lk*4 + r;
        float v = acc[i][j][r] + bn_;
        if (EPI==0){
          size_t trow = (size_t)off1[e] + bm0 + mloc;
          t1[trow*N + n] = f2bf(gelu_fast(v));
        } else {
          int mg = bm0 + mloc;
          if ((uint)mg < cnt[e]){
            int tok = toks[e*CH + mg];
            float g = gates[(size_t)tok*NE + e];
            resid[(size_t)tok*N + n] += g*v;
          }
        }
      }
    }
  }
}

// ---------- final: LN(resid) -> LN -> @w_cls + b_cls ----------
__global__ __launch_bounds__(64) void final_kernel(
    const float* __restrict__ resid,
    const float* __restrict__ g_moe, const float* __restrict__ beta_moe,
    const float* __restrict__ g_out, const float* __restrict__ beta_out,
    const float* __restrict__ w_cls, const float* __restrict__ b_cls,
    float* __restrict__ out)
{
  int tok = blockIdx.x; int l = threadIdx.x;
  const float* row = resid + (size_t)tok*DM;
  float u[16];
  double s=0.0,q=0.0;
  #pragma unroll
  for (int r=0;r<16;++r){ u[r]=row[l + 64*r]; s+=u[r]; q+=(double)u[r]*u[r]; }
  s=wredd(s); q=wredd(q);
  double m1 = s*(1.0/1024.0), v1 = q*(1.0/1024.0)-m1*m1;
  double rs1 = 1.0/sqrt(v1+1e-5);
  float tv[16]; double s2=0.0,q2=0.0;
  #pragma unroll
  for (int r=0;r<16;++r){
    int j = l+64*r;
    float vv = (float)((u[r]-m1)*rs1)*g_moe[j] + beta_moe[j];
    tv[r]=vv; s2+=vv; q2+=(double)vv*vv;
  }
  s2=wredd(s2); q2=wredd(q2);
  double m2=s2*(1.0/1024.0), v2=q2*(1.0/1024.0)-m2*m2;
  double rs2=1.0/sqrt(v2+1e-5);
  double p0=0.0,p1=0.0;
  #pragma unroll
  for (int r=0;r<16;++r){
    int j=l+64*r;
    double y=((double)tv[r]-m2)*rs2*(double)g_out[j]+(double)beta_out[j];
    p0+=y*(double)w_cls[j*2]; p1+=y*(double)w_cls[j*2+1];
  }
  p0=wredd(p0); p1=wredd(p1);
  if (l==0){
    out[(size_t)tok*2  ]=(float)(p0+(double)b_cls[0]);
    out[(size_t)tok*2+1]=(float)(p1+(double)b_cls[1]);
  }
}

extern "C" void kernel_launch(void* const* d_in, const int* in_sizes, int n_in,
                              void* d_out, int out_size, void* d_ws, size_t ws_size,
                              hipStream_t stream)
{
  (void)in_sizes; (void)n_in; (void)out_size;
  const float* x       = (const float*)d_in[0];
  const float* w_in    = (const float*)d_in[1];
  const float* b_in    = (const float*)d_in[2];
  const float* g_in    = (const float*)d_in[3];
  const float* beta_in = (const float*)d_in[4];
  const float* w_gate  = (const float*)d_in[5];
  const float* w1      = (const float*)d_in[6];
  const float* b1      = (const float*)d_in[7];
  const float* w2      = (const float*)d_in[8];
  const float* b2      = (const float*)d_in[9];
  const float* g_moe   = (const float*)d_in[10];
  const float* beta_mo = (const float*)d_in[11];
  const float* g_out   = (const float*)d_in[12];
  const float* beta_ou = (const float*)d_in[13];
  const float* w_cls   = (const float*)d_in[14];
  const float* b_cls   = (const float*)d_in[15];
  float* out = (float*)d_out;

  // ---- workspace carve ----
  char* p = (char*)d_ws;
  ushort* w1t   = (ushort*)p; p += (size_t)NE*HD*DM*2;     // 33.5 MB
  ushort* w2t   = (ushort*)p; p += (size_t)NE*DM*HD*2;     // 33.5 MB
  ushort* hbf   = (ushort*)p; p += (size_t)NTOK*DM*2;      // 33.5 MB
  float*  resid = (float*)p;  p += (size_t)NTOK*DM*4;      // 67 MB (also router-GEMM y)
  float*  gates = (float*)p;  p += (size_t)NTOK*NE*4;
  int*    selmk = (int*)p;    p += (size_t)NTOK*4;
  int*    ids1  = (int*)p;    p += (size_t)NE*NTOK*4;
  int*    g2row = (int*)p;    p += (size_t)2*NE*NTOK*4;
  int*    g2tok = (int*)p;    p += (size_t)2*NE*NTOK*4;
  ushort* wt3   = (ushort*)p; p += (size_t)DM*768*2;       // 1.5 MB
  float*  wgt   = (float*)p;  p += (size_t)NE*DM*4;        // 32 KB
  uint*   bc1   = (uint*)p;   p += (size_t)64*8*4;
  uint*   bc2   = (uint*)p;   p += (size_t)64*16*4;
  uint*   meta  = (uint*)p;   p += (size_t)MT_TOTAL*4;
  size_t fixed = (size_t)(p - (char*)d_ws);

  const size_t xs3_bytes = (size_t)NTOK*768*2;             // 25.2 MB
  size_t t1b2 = ((size_t)2*(NTOK/2)+1024)*HD*2;
  size_t t1b4 = ((size_t)2*(NTOK/4)+1024)*HD*2;
  int nch = 8;
  if (ws_size >= fixed + (t1b2 > xs3_bytes ? t1b2 : xs3_bytes)) nch = 2;
  else if (ws_size >= fixed + (t1b4 > xs3_bytes ? t1b4 : xs3_bytes)) nch = 4;
  const int CH  = NTOK/nch;
  const int TPC = CH/256;
  ushort* t1  = (ushort*)p;       // t1 region (also xs3 alias; xs3 dead before t1 written)
  ushort* xs3 = (ushort*)p;

  // ---- router path (bf16x3 MFMA emulated-f32) ----
  split_x_kernel<<<dim3(NTOK*D_IN/4/256), 256, 0, stream>>>(x, xs3);
  transpose_split3_kernel<<<dim3(DM/32, D_IN/32), 256, 0, stream>>>(w_in, wt3);
  wgate_t_kernel<<<dim3(NE), 256, 0, stream>>>(w_gate, wgt);
  transpose_bf16_kernel<<<dim3(HD/32, DM/32, NE), 256, 0, stream>>>(w1, w1t, DM, HD);
  transpose_bf16_kernel<<<dim3(DM/32, HD/32, NE), 256, 0, stream>>>(w2, w2t, HD, DM);

  gemm_router<<<dim3(DM/128, NTOK/128), 256, 0, stream>>>(xs3, wt3, b_in, resid);
  ln_router_kernel<<<dim3(NTOK/4), 256, 0, stream>>>(g_in, beta_in, wgt,
                                                     hbf, resid, gates, selmk);

  hipMemsetAsync(ids1, 0, (size_t)NE*NTOK*4, stream);
  hipMemsetAsync(g2row, 0, (size_t)2*NE*NTOK*4, stream);
  hipMemsetAsync(g2tok, 0, (size_t)2*NE*NTOK*4, stream);

  builder_count<<<dim3(NTOK/256), 256, 0, stream>>>(selmk, bc1, bc2);
  builder_scan<<<dim3(1), 256, 0, stream>>>(bc1, bc2, meta, nch, TPC);
  builder_fill<<<dim3(NTOK/256), 256, 0, stream>>>(selmk, meta, ids1, g2row, g2tok, CH);

  for (int c = 0; c < nch; ++c) {
    gemm_sparse<0><<<dim3(NE*(CH/128)*(HD/128)), 256, 0, stream>>>(
        hbf, w1t, ids1 + (size_t)c*8*CH, nullptr,
        meta+MT_P1+c*8, nullptr, meta+MT_OFF1+c*8,
        b1, nullptr, t1, nullptr, DM, HD, CH);
    for (int s = 0; s < 2; ++s) {
      gemm_sparse<1><<<dim3(NE*(CH/128)*(DM/128)), 256, 0, stream>>>(
          t1, w2t, g2row + (size_t)(c*2+s)*8*CH, g2tok + (size_t)(c*2+s)*8*CH,
          meta+MT_PCNT2+c*16+s*8, meta+MT_CNT2+c*16+s*8, nullptr,
          b2, gates, nullptr, resid, HD, DM, CH);
    }
  }

  final_kernel<<<dim3(NTOK), 64, 0, stream>>>(resid, g_moe, beta_mo, g_out, beta_ou,
                                              w_cls, b_cls, out);
}

// Round 5
// 926.251 us; speedup vs baseline: 1.3739x; 1.3739x over previous
//
#include <hip/hip_runtime.h>
#include <hip/hip_bf16.h>

#define D_IN 256
#define DM   1024
#define HD   2048
#define NE   8
#define NTOK 16384

typedef __attribute__((ext_vector_type(8))) short short8;
typedef __attribute__((ext_vector_type(4))) float f32x4;
typedef unsigned int uint;

// ---- meta layout (uint indices) ----
#define MT_TOFF1 0      // [64][8]
#define MT_TOFF2 512    // [64][16]
#define MT_CNT1  1536   // [8][8]
#define MT_P1    1600   // [8][8]    roundup256(cnt1)
#define MT_OFF1  1664   // [8][8]
#define MT_CNT2  1728   // [8][16]
#define MT_PCNT2 1856   // [8][16]   roundup128(cnt2)
#define MT_TOTAL 1984

__device__ inline ushort f2bf(float v){
  __hip_bfloat16 b = __float2bfloat16(v);
  return *reinterpret_cast<ushort*>(&b);
}
__device__ inline float bf2f(ushort u){
  __hip_bfloat16 b = *reinterpret_cast<__hip_bfloat16*>(&u);
  return __bfloat162float(b);
}

// gelu tanh-approx via identity 0.5*(1+tanh(u)) = sigmoid(2u)
__device__ inline float gelu_fast(float x){
  float u = 0.7978845608028654f * x * (1.0f + 0.044715f*x*x);
  return x / (1.0f + __expf(-2.0f*u));
}

__device__ inline void gload16(const void* g, void* l){
  __builtin_amdgcn_global_load_lds(
      (const __attribute__((address_space(1))) void*)g,
      (__attribute__((address_space(3))) void*)l, 16, 0, 0);
}

// ---------- transpose [R][C] f32 -> [C][R] bf16 (per expert, blockIdx.z) ----------
__global__ __launch_bounds__(256) void transpose_bf16_kernel(
    const float* __restrict__ src, ushort* __restrict__ dst, int R, int C)
{
  __shared__ float tile[32][33];
  int e = blockIdx.z;
  src += (size_t)e*R*C; dst += (size_t)e*R*C;
  int c0 = blockIdx.x*32, r0 = blockIdx.y*32;
  int tx = threadIdx.x & 31, ty = threadIdx.x >> 5;
  #pragma unroll
  for (int rr = ty; rr < 32; rr += 8)
    tile[rr][tx] = src[(size_t)(r0+rr)*C + c0+tx];
  __syncthreads();
  #pragma unroll
  for (int rr = ty; rr < 32; rr += 8)
    dst[(size_t)(c0+rr)*R + r0+tx] = f2bf(tile[tx][rr]);
}

// ---------- build xs6 [NTOK][1536]: A slots = [hi|mid|hi|mid|lo|hi] ----------
__global__ __launch_bounds__(64) void build_xs6(
    const float* __restrict__ x, ushort* __restrict__ xs6)
{
  int row = blockIdx.x; int t = threadIdx.x;
  const float* xr = x + (size_t)row*D_IN;
  ushort* o = xs6 + (size_t)row*1536;
  #pragma unroll
  for (int i=0;i<4;++i){
    int c = t*4+i;
    float f = xr[c];
    ushort h = f2bf(f);        float fh = bf2f(h);
    ushort m = f2bf(f - fh);   float fm = bf2f(m);
    ushort lo = f2bf(f - fh - fm);
    o[c]      = h;  o[512+c]  = h;  o[1280+c] = h;
    o[256+c]  = m;  o[768+c]  = m;
    o[1024+c] = lo;
  }
}

// ---------- build wt6 [DM][1536] from w_in [D_IN][DM]: B slots = [hi|hi|mid|mid|hi|lo] ----------
__global__ __launch_bounds__(256) void build_wt6(
    const float* __restrict__ src, ushort* __restrict__ dst)
{
  __shared__ float tile[32][33];
  int c0 = blockIdx.x*32, r0 = blockIdx.y*32;   // c over DM, r over D_IN
  int tx = threadIdx.x & 31, ty = threadIdx.x >> 5;
  #pragma unroll
  for (int rr = ty; rr < 32; rr += 8)
    tile[rr][tx] = src[(size_t)(r0+rr)*DM + c0+tx];
  __syncthreads();
  #pragma unroll
  for (int rr = ty; rr < 32; rr += 8){
    float f = tile[tx][rr];     // element (k=r0+tx, d=c0+rr)
    ushort h = f2bf(f);        float fh = bf2f(h);
    ushort m = f2bf(f - fh);   float fm = bf2f(m);
    ushort lo = f2bf(f - fh - fm);
    ushort* d = dst + (size_t)(c0+rr)*1536 + r0 + tx;
    d[0]    = h;  d[256]  = h;  d[1024] = h;
    d[512]  = m;  d[768]  = m;
    d[1280] = lo;
  }
}

// ---------- w_gate[1024][8] -> wgt[8][1024] ----------
__global__ __launch_bounds__(256) void wgate_t_kernel(
    const float* __restrict__ w_gate, float* __restrict__ wgt)
{
  int e = blockIdx.x;
  for (int j = threadIdx.x; j < DM; j += 256)
    wgt[(size_t)e*DM + j] = w_gate[(size_t)j*NE + e];
}

// ================= 8-phase 256x256 BK=64 GEMM (m201-style, plain HIP) =================
// MODE 0: dense A [M][K], out f32 y = A*BT^T + bias       (router)
// MODE 1: A rows gathered via rows[], out t1 = bf16(gelu(v + bias[e])), expert z-grid
// st_16x32 swizzle: byte ^= ((byte>>9)&1)<<5, applied on SOURCE col (stage) and ds_read.
template<int MODE>
__global__ __launch_bounds__(512, 2) void gemm8p(
    const ushort* __restrict__ A,
    const ushort* __restrict__ BT,      // MODE1: [E][N][K]
    const int*   __restrict__ rows,
    const uint*  __restrict__ pcnt,
    const uint*  __restrict__ off1,
    const float* __restrict__ bias,
    float* __restrict__ yout,
    ushort* __restrict__ t1,
    int N, int K, int CH)
{
  __shared__ ushort lds[2][2][2][8192];   // [dbuf][A/B][half][16KB]
  const int tid = threadIdx.x;
  const int wid = tid>>6, l = tid&63;
  const int wm = wid>>2, wn = wid&3;
  const int lr = l&15, lk = l>>4;

  int e = 0;
  const int bn0 = blockIdx.x*256;
  const int bm0 = blockIdx.y*256;
  if (MODE==1){
    e = blockIdx.z;
    if ((uint)bm0 >= pcnt[e]) return;
  }
  const ushort* Bbase = BT + (MODE==1 ? (size_t)e*N*K : (size_t)0);

  // per-thread stage sources (pre-swizzled column) — 2 halves x 2 loads each
  const ushort* aS[2][2]; const ushort* bS[2][2];
  #pragma unroll
  for (int h=0;h<2;++h){
    #pragma unroll
    for (int j=0;j<2;++j){
      int idx = j*512 + tid;                       // 0..1023
      int r   = idx>>3;                            // 0..127 (row in half)
      int cb  = ((idx&7)*16) ^ (((r>>2)&1)<<5);    // swizzled byte col
      if (MODE==1){
        int id = rows[e*CH + bm0 + h*128 + r];
        aS[h][j] = A + (size_t)id*K + (cb>>1);
      } else {
        aS[h][j] = A + (size_t)(bm0 + h*128 + r)*K + (cb>>1);
      }
      bS[h][j] = Bbase + (size_t)(bn0 + h*128 + r)*K + (cb>>1);
    }
  }

  auto stageA = [&](int db, int kt){
    #pragma unroll
    for (int h=0;h<2;++h)
      #pragma unroll
      for (int j=0;j<2;++j)
        gload16(aS[h][j] + kt, &lds[db][0][h][(j*512+tid)*8]);
  };
  auto stageB = [&](int db, int kt){
    #pragma unroll
    for (int h=0;h<2;++h)
      #pragma unroll
      for (int j=0;j<2;++j)
        gload16(bS[h][j] + kt, &lds[db][1][h][(j*512+tid)*8]);
  };

  // prologue: tiles 0 and 1
  stageA(0, 0);  stageB(0, 0);
  stageA(1, 64); stageB(1, 64);
  asm volatile("s_waitcnt vmcnt(8)" ::: "memory");
  __builtin_amdgcn_s_barrier();

  const char* aB; const char* bB;
  auto ldA = [&](int frA, int ks)->short8{
    int r = frA*16 + lr;
    int off = r*128 + ((ks*64 + lk*16) ^ (((r>>2)&1)<<5));
    return *(const short8*)(aB + off);
  };
  auto ldB = [&](int fc, int ks)->short8{
    int r = (wn&1)*64 + fc*16 + lr;
    int off = r*128 + ((ks*64 + lk*16) ^ (((r>>2)&1)<<5));
    return *(const short8*)(bB + off);
  };

  short8 aR[4][2]; short8 bR[4][2];
  f32x4 acc[8][4] = {};
  const int NT = K>>6;

  for (int T=0; T<NT; ++T){
    const int cur = T&1;
    aB = (const char*)&lds[cur][0][wm][0];
    bB = (const char*)&lds[cur][1][wn>>1][0];
    const bool pf = (T+2 < NT);
    const int kpf = (T+2)<<6;

    // ---- ph0: A rh0 (8 reads) + B c0-1 (4 reads); MFMA quad(0,0)
    #pragma unroll
    for (int fr=0;fr<4;++fr){ aR[fr][0]=ldA(fr,0); aR[fr][1]=ldA(fr,1); }
    #pragma unroll
    for (int fc=0;fc<2;++fc){ bR[fc][0]=ldB(fc,0); bR[fc][1]=ldB(fc,1); }
    __builtin_amdgcn_s_barrier();
    __builtin_amdgcn_s_setprio(1);
    #pragma unroll
    for (int fr=0;fr<4;++fr)
      #pragma unroll
      for (int fc=0;fc<2;++fc)
        #pragma unroll
        for (int ks=0;ks<2;++ks)
          acc[fr][fc] = __builtin_amdgcn_mfma_f32_16x16x32_bf16(aR[fr][ks], bR[fc][ks], acc[fr][fc], 0,0,0);
    __builtin_amdgcn_s_setprio(0);
    __builtin_amdgcn_s_barrier();

    // ---- ph1: B c2-3 (4 reads); MFMA quad(0,1)
    #pragma unroll
    for (int fc=0;fc<2;++fc){ bR[2+fc][0]=ldB(2+fc,0); bR[2+fc][1]=ldB(2+fc,1); }
    __builtin_amdgcn_s_barrier();
    __builtin_amdgcn_s_setprio(1);
    #pragma unroll
    for (int fr=0;fr<4;++fr)
      #pragma unroll
      for (int fc=0;fc<2;++fc)
        #pragma unroll
        for (int ks=0;ks<2;++ks)
          acc[fr][2+fc] = __builtin_amdgcn_mfma_f32_16x16x32_bf16(aR[fr][ks], bR[2+fc][ks], acc[fr][2+fc], 0,0,0);
    __builtin_amdgcn_s_setprio(0);
    __builtin_amdgcn_s_barrier();

    // ---- ph2: A rh1 (8 reads) + stage B(T+2); MFMA quad(1,1)
    #pragma unroll
    for (int fr=0;fr<4;++fr){ aR[fr][0]=ldA(4+fr,0); aR[fr][1]=ldA(4+fr,1); }
    if (pf) stageB(cur, kpf);
    __builtin_amdgcn_s_barrier();
    __builtin_amdgcn_s_setprio(1);
    #pragma unroll
    for (int fr=0;fr<4;++fr)
      #pragma unroll
      for (int fc=0;fc<2;++fc)
        #pragma unroll
        for (int ks=0;ks<2;++ks)
          acc[4+fr][2+fc] = __builtin_amdgcn_mfma_f32_16x16x32_bf16(aR[fr][ks], bR[2+fc][ks], acc[4+fr][2+fc], 0,0,0);
    __builtin_amdgcn_s_setprio(0);
    __builtin_amdgcn_s_barrier();

    // ---- ph3: stage A(T+2); counted vmcnt; MFMA quad(1,0)
    if (pf) stageA(cur, kpf);
    if (pf)              { asm volatile("s_waitcnt vmcnt(8)" ::: "memory"); }
    else if (T+1 < NT)   { asm volatile("s_waitcnt vmcnt(0)" ::: "memory"); }
    __builtin_amdgcn_s_barrier();
    __builtin_amdgcn_s_setprio(1);
    #pragma unroll
    for (int fr=0;fr<4;++fr)
      #pragma unroll
      for (int fc=0;fc<2;++fc)
        #pragma unroll
        for (int ks=0;ks<2;++ks)
          acc[4+fr][fc] = __builtin_amdgcn_mfma_f32_16x16x32_bf16(aR[fr][ks], bR[fc][ks], acc[4+fr][fc], 0,0,0);
    __builtin_amdgcn_s_setprio(0);
    __builtin_amdgcn_s_barrier();
  }

  // ---- epilogue
  const float* bp = bias + (MODE==1 ? (size_t)e*N : (size_t)0);
  #pragma unroll
  for (int fr=0;fr<8;++fr){
    #pragma unroll
    for (int fc=0;fc<4;++fc){
      int n = bn0 + wn*64 + fc*16 + lr;
      float bb = bp[n];
      #pragma unroll
      for (int v=0;v<4;++v){
        int mloc = wm*128 + fr*16 + lk*4 + v;
        float val = acc[fr][fc][v] + bb;
        if (MODE==0){
          yout[(size_t)(bm0+mloc)*N + n] = val;
        } else {
          t1[((size_t)off1[e] + bm0 + mloc)*N + n] = f2bf(gelu_fast(val));
        }
      }
    }
  }
}

// ---------- LN + logits + softmax top2 (wave per token), in-place on y ----------
__device__ inline double wredd(double v){
  #pragma unroll
  for (int o=32;o>0;o>>=1) v += __shfl_xor(v, o, 64);
  return v;
}

__global__ __launch_bounds__(256) void ln_router_kernel(
    const float* __restrict__ g_in, const float* __restrict__ beta_in,
    const float* __restrict__ wgt,
    ushort* __restrict__ hbf, float* __restrict__ resid,
    float* __restrict__ gates, int* __restrict__ selmask)
{
  int tok = blockIdx.x*4 + (threadIdx.x>>6);
  int l = threadIdx.x & 63;
  float* row = resid + (size_t)tok*DM;
  float u[16];
  double s=0.0, q=0.0;
  #pragma unroll
  for (int r=0;r<16;++r){ u[r]=row[l+64*r]; s+=u[r]; q+=(double)u[r]*u[r]; }
  s = wredd(s); q = wredd(q);
  double mean = s*(1.0/1024.0);
  double var  = q*(1.0/1024.0) - mean*mean;
  double rstd = 1.0/sqrt(var + 1e-5);

  double lg[NE];
  #pragma unroll
  for (int e=0;e<NE;++e) lg[e]=0.0;
  float hv[16];
  #pragma unroll
  for (int r=0;r<16;++r){
    int j = l + 64*r;
    double v = ((double)u[r]-mean)*rstd*(double)g_in[j] + (double)beta_in[j];
    hv[r] = (float)v;
    #pragma unroll
    for (int e=0;e<NE;++e) lg[e] += v*(double)wgt[(size_t)e*DM + j];
  }
  #pragma unroll
  for (int r=0;r<16;++r){
    int j = l + 64*r;
    row[j] = hv[r];
    hbf[(size_t)tok*DM + j] = f2bf(hv[r]);
  }
  #pragma unroll
  for (int e=0;e<NE;++e) lg[e] = wredd(lg[e]);

  if (l==0){
    double mx = lg[0];
    #pragma unroll
    for (int e=1;e<NE;++e) mx = lg[e]>mx ? lg[e] : mx;
    double p[NE]; double sum=0.0;
    #pragma unroll
    for (int e=0;e<NE;++e){ p[e]=exp(lg[e]-mx); sum+=p[e]; }
    #pragma unroll
    for (int e=0;e<NE;++e) p[e]/=sum;
    int i1=0;
    for (int e=1;e<NE;++e) if (p[e]>p[i1]) i1=e;
    int i2=-1;
    for (int e=0;e<NE;++e){ if (e==i1) continue; if (i2<0 || p[e]>p[i2]) i2=e; }
    double denom = p[i1]+p[i2]+1e-9;
    float g[NE];
    #pragma unroll
    for (int e=0;e<NE;++e) g[e]=0.f;
    g[i1]=(float)(p[i1]/denom);
    g[i2]=(float)(p[i2]/denom);
    #pragma unroll
    for (int e=0;e<NE;++e) gates[(size_t)tok*NE+e]=g[e];
    selmask[tok] = (1<<i1)|(1<<i2);
  }
}

// ---------- builders ----------
__global__ __launch_bounds__(256) void builder_count(
    const int* __restrict__ selmask, uint* __restrict__ bc1, uint* __restrict__ bc2)
{
  __shared__ uint c1[8], c2s[16];
  int b = blockIdx.x, tid = threadIdx.x;
  if (tid<8) c1[tid]=0;
  if (tid<16) c2s[tid]=0;
  __syncthreads();
  int m = selmask[b*256+tid];
  int ea = __ffs(m)-1, eb = 31-__clz(m);
  atomicAdd(&c1[ea],1u); atomicAdd(&c1[eb],1u);
  atomicAdd(&c2s[ea],1u); atomicAdd(&c2s[8+eb],1u);
  __syncthreads();
  if (tid<8) bc1[b*8+tid]=c1[tid];
  if (tid<16) bc2[b*16+tid]=c2s[tid];
}

__global__ __launch_bounds__(256) void builder_scan(
    const uint* __restrict__ bc1, const uint* __restrict__ bc2,
    uint* __restrict__ meta, int nch, int TPC)
{
  int tid = threadIdx.x;
  int c = tid/24, k = tid%24;
  if (c < nch){
    if (k < 8){
      uint run=0;
      for (int b=c*TPC; b<(c+1)*TPC; ++b){ meta[MT_TOFF1 + b*8 + k] = run; run += bc1[b*8+k]; }
      meta[MT_CNT1 + c*8 + k] = run;
    } else {
      int k2 = k-8;
      uint run=0;
      for (int b=c*TPC; b<(c+1)*TPC; ++b){ meta[MT_TOFF2 + b*16 + k2] = run; run += bc2[b*16+k2]; }
      meta[MT_CNT2 + c*16 + k2] = run;
      meta[MT_PCNT2 + c*16 + k2] = ((run + 127u)/128u)*128u;
    }
  }
  __syncthreads();
  if (tid < nch){
    uint off=0;
    for (int e=0;e<8;++e){
      uint cn = meta[MT_CNT1 + tid*8 + e];
      uint p = ((cn+255u)/256u)*256u;      // 256-pad for the 8-phase BM=256 kernel
      meta[MT_P1 + tid*8 + e] = p;
      meta[MT_OFF1 + tid*8 + e] = off;
      off += p;
    }
  }
}

__device__ inline int exclscan256(int v, int* sc, int tid){
  sc[tid]=v; __syncthreads();
  #pragma unroll
  for (int o=1;o<256;o<<=1){
    int x = (tid>=o) ? sc[tid-o] : 0;
    __syncthreads();
    sc[tid]+=x;
    __syncthreads();
  }
  int incl = sc[tid]; __syncthreads();
  return incl - v;
}

__global__ __launch_bounds__(256) void builder_fill(
    const int* __restrict__ selmask, const uint* __restrict__ meta,
    int* __restrict__ ids1, int* __restrict__ g2row, int* __restrict__ g2tok,
    int CH)
{
  __shared__ int sc[256];
  int b = blockIdx.x, tid = threadIdx.x;
  int t = b*256 + tid;
  int c = t / CH;
  int m = selmask[t];
  int ea = __ffs(m)-1, eb = 31-__clz(m);
  int ja=0, jb=0;
  for (int e=0;e<8;++e){
    int r0 = exclscan256((ea==e)?1:0, sc, tid);
    if (ea==e) ja = r0;
    int r1 = exclscan256((eb==e)?1:0, sc, tid);
    if (eb==e) jb = r1;
  }
  {
    uint j    = meta[MT_TOFF2 + b*16 + ea] + (uint)ja;
    uint pos1 = j;
    uint row  = meta[MT_OFF1 + c*8 + ea] + pos1;
    ids1[(c*8+ea)*CH + pos1] = t;
    g2row[((c*2+0)*8+ea)*CH + j] = (int)row;
    g2tok[((c*2+0)*8+ea)*CH + j] = t;
  }
  {
    uint j    = meta[MT_TOFF2 + b*16 + 8 + eb] + (uint)jb;
    uint pos1 = meta[MT_CNT2 + c*16 + eb] + j;
    uint row  = meta[MT_OFF1 + c*8 + eb] + pos1;
    ids1[(c*8+eb)*CH + pos1] = t;
    g2row[((c*2+1)*8+eb)*CH + j] = (int)row;
    g2tok[((c*2+1)*8+eb)*CH + j] = t;
  }
}

// ---------- EPI1: sparse gather-GEMM, round-3 proven 128^2 m97 structure ----------
template<int EPI>
__global__ __launch_bounds__(256) void gemm_sparse(
    const ushort* __restrict__ Abase,
    const ushort* __restrict__ BT,
    const int*   __restrict__ rows,
    const int*   __restrict__ toks,
    const uint*  __restrict__ pcnt,
    const uint*  __restrict__ cnt,
    const uint*  __restrict__ off1,
    const float* __restrict__ bias,
    const float* __restrict__ gates,
    ushort* __restrict__ t1,
    float*  __restrict__ resid,
    int K, int N, int CH)
{
  const int e = blockIdx.z;
  const int bm0 = blockIdx.y*128;
  if ((uint)bm0 >= pcnt[e]) return;
  const int bn0 = blockIdx.x*128;

  __shared__ ushort As[128*32];
  __shared__ ushort Bs[128*32];
  const int tid = threadIdx.x;
  const int w = tid>>6, l = tid&63;
  const int wm = w>>1, wn = w&1;
  const int lr = l&15, lk = l>>4;
  const int rsub = l>>2, csub = (l&3)*8;

  const ushort* ag[2]; const ushort* bg[2];
  ushort* al[2]; ushort* bl[2];
  #pragma unroll
  for (int i=0;i<2;++i){
    int ra = w*32 + i*16 + rsub;
    int id = rows[e*CH + bm0 + ra];
    ag[i] = Abase + (size_t)id*K + csub;
    int rb = bn0 + w*32 + i*16 + rsub;
    bg[i] = BT + (size_t)e*N*K + (size_t)rb*K + csub;
    al[i] = (ushort*)As + (w*32 + i*16)*32;
    bl[i] = (ushort*)Bs + (w*32 + i*16)*32;
  }

  f32x4 zero = {0.f,0.f,0.f,0.f};
  f32x4 acc[4][4];
  #pragma unroll
  for (int i=0;i<4;++i){
    #pragma unroll
    for (int j=0;j<4;++j) acc[i][j]=zero;
  }

  for (int kt = 0; kt < K; kt += 32) {
    #pragma unroll
    for (int i=0;i<2;++i){
      gload16(ag[i]+kt, al[i]);
      gload16(bg[i]+kt, bl[i]);
    }
    __syncthreads();
    short8 af[4], bf[4];
    #pragma unroll
    for (int i=0;i<4;++i) af[i] = *(const short8*)(As + (wm*64 + i*16 + lr)*32 + lk*8);
    #pragma unroll
    for (int j=0;j<4;++j) bf[j] = *(const short8*)(Bs + (wn*64 + j*16 + lr)*32 + lk*8);
    #pragma unroll
    for (int i=0;i<4;++i){
      #pragma unroll
      for (int j=0;j<4;++j)
        acc[i][j] = __builtin_amdgcn_mfma_f32_16x16x32_bf16(af[i], bf[j], acc[i][j], 0, 0, 0);
    }
    __syncthreads();
  }

  #pragma unroll
  for (int i=0;i<4;++i){
    #pragma unroll
    for (int j=0;j<4;++j){
      int n = bn0 + wn*64 + j*16 + lr;
      float bn_ = bias[(size_t)e*N + n];
      #pragma unroll
      for (int r=0;r<4;++r){
        int mloc = wm*64 + i*16 + lk*4 + r;
        float v = acc[i][j][r] + bn_;
        if (EPI==0){
          size_t trow = (size_t)off1[e] + bm0 + mloc;
          t1[trow*N + n] = f2bf(gelu_fast(v));
        } else {
          int mg = bm0 + mloc;
          if ((uint)mg < cnt[e]){
            int tok = toks[e*CH + mg];
            float g = gates[(size_t)tok*NE + e];
            resid[(size_t)tok*N + n] += g*v;
          }
        }
      }
    }
  }
}

// ---------- final: LN(resid) -> LN -> @w_cls + b_cls ----------
__global__ __launch_bounds__(64) void final_kernel(
    const float* __restrict__ resid,
    const float* __restrict__ g_moe, const float* __restrict__ beta_moe,
    const float* __restrict__ g_out, const float* __restrict__ beta_out,
    const float* __restrict__ w_cls, const float* __restrict__ b_cls,
    float* __restrict__ out)
{
  int tok = blockIdx.x; int l = threadIdx.x;
  const float* row = resid + (size_t)tok*DM;
  float u[16];
  double s=0.0,q=0.0;
  #pragma unroll
  for (int r=0;r<16;++r){ u[r]=row[l + 64*r]; s+=u[r]; q+=(double)u[r]*u[r]; }
  s=wredd(s); q=wredd(q);
  double m1 = s*(1.0/1024.0), v1 = q*(1.0/1024.0)-m1*m1;
  double rs1 = 1.0/sqrt(v1+1e-5);
  float tv[16]; double s2=0.0,q2=0.0;
  #pragma unroll
  for (int r=0;r<16;++r){
    int j = l+64*r;
    float vv = (float)((u[r]-m1)*rs1)*g_moe[j] + beta_moe[j];
    tv[r]=vv; s2+=vv; q2+=(double)vv*vv;
  }
  s2=wredd(s2); q2=wredd(q2);
  double m2=s2*(1.0/1024.0), v2=q2*(1.0/1024.0)-m2*m2;
  double rs2=1.0/sqrt(v2+1e-5);
  double p0=0.0,p1=0.0;
  #pragma unroll
  for (int r=0;r<16;++r){
    int j=l+64*r;
    double y=((double)tv[r]-m2)*rs2*(double)g_out[j]+(double)beta_out[j];
    p0+=y*(double)w_cls[j*2]; p1+=y*(double)w_cls[j*2+1];
  }
  p0=wredd(p0); p1=wredd(p1);
  if (l==0){
    out[(size_t)tok*2  ]=(float)(p0+(double)b_cls[0]);
    out[(size_t)tok*2+1]=(float)(p1+(double)b_cls[1]);
  }
}

extern "C" void kernel_launch(void* const* d_in, const int* in_sizes, int n_in,
                              void* d_out, int out_size, void* d_ws, size_t ws_size,
                              hipStream_t stream)
{
  (void)in_sizes; (void)n_in; (void)out_size;
  const float* x       = (const float*)d_in[0];
  const float* w_in    = (const float*)d_in[1];
  const float* b_in    = (const float*)d_in[2];
  const float* g_in    = (const float*)d_in[3];
  const float* beta_in = (const float*)d_in[4];
  const float* w_gate  = (const float*)d_in[5];
  const float* w1      = (const float*)d_in[6];
  const float* b1      = (const float*)d_in[7];
  const float* w2      = (const float*)d_in[8];
  const float* b2      = (const float*)d_in[9];
  const float* g_moe   = (const float*)d_in[10];
  const float* beta_mo = (const float*)d_in[11];
  const float* g_out   = (const float*)d_in[12];
  const float* beta_ou = (const float*)d_in[13];
  const float* w_cls   = (const float*)d_in[14];
  const float* b_cls   = (const float*)d_in[15];
  float* out = (float*)d_out;

  // ---- workspace carve ----
  char* p = (char*)d_ws;
  ushort* w1t   = (ushort*)p; p += (size_t)NE*HD*DM*2;
  ushort* w2t   = (ushort*)p; p += (size_t)NE*DM*HD*2;
  ushort* hbf   = (ushort*)p; p += (size_t)NTOK*DM*2;
  float*  resid = (float*)p;  p += (size_t)NTOK*DM*4;      // also router-GEMM y
  float*  gates = (float*)p;  p += (size_t)NTOK*NE*4;
  int*    selmk = (int*)p;    p += (size_t)NTOK*4;
  int*    ids1  = (int*)p;    p += (size_t)NE*NTOK*4;
  int*    g2row = (int*)p;    p += (size_t)2*NE*NTOK*4;
  int*    g2tok = (int*)p;    p += (size_t)2*NE*NTOK*4;
  float*  wgt   = (float*)p;  p += (size_t)NE*DM*4;
  uint*   bc1   = (uint*)p;   p += (size_t)64*8*4;
  uint*   bc2   = (uint*)p;   p += (size_t)64*16*4;
  uint*   meta  = (uint*)p;   p += (size_t)MT_TOTAL*4;
  size_t fixed = (size_t)(p - (char*)d_ws);

  // tail region: {xs6 (50.3MB) + wt6 (3MB)} early, then reused as t1
  const size_t xs6_bytes = (size_t)NTOK*1536*2;
  const size_t wt6_bytes = (size_t)DM*1536*2;
  const size_t router_bytes = xs6_bytes + wt6_bytes;
  size_t t1b2 = ((size_t)2*(NTOK/2)+2048)*HD*2;
  size_t t1b4 = ((size_t)2*(NTOK/4)+2048)*HD*2;
  int nch = 8;
  if (ws_size >= fixed + (t1b2 > router_bytes ? t1b2 : router_bytes)) nch = 2;
  else if (ws_size >= fixed + (t1b4 > router_bytes ? t1b4 : router_bytes)) nch = 4;
  const int CH  = NTOK/nch;
  const int TPC = CH/256;
  ushort* t1  = (ushort*)p;
  ushort* xs6 = (ushort*)p;                       // aliases t1 (dead before t1 written)
  ushort* wt6 = (ushort*)(p + xs6_bytes);

  // ---- router path (bf16x3 emulated-f32 as one K=1536 GEMM) ----
  build_xs6<<<dim3(NTOK), 64, 0, stream>>>(x, xs6);
  build_wt6<<<dim3(DM/32, D_IN/32), 256, 0, stream>>>(w_in, wt6);
  wgate_t_kernel<<<dim3(NE), 256, 0, stream>>>(w_gate, wgt);
  transpose_bf16_kernel<<<dim3(HD/32, DM/32, NE), 256, 0, stream>>>(w1, w1t, DM, HD);
  transpose_bf16_kernel<<<dim3(DM/32, HD/32, NE), 256, 0, stream>>>(w2, w2t, HD, DM);

  gemm8p<0><<<dim3(DM/256, NTOK/256), 512, 0, stream>>>(
      xs6, wt6, nullptr, nullptr, nullptr, b_in, resid, nullptr, DM, 1536, CH);
  ln_router_kernel<<<dim3(NTOK/4), 256, 0, stream>>>(g_in, beta_in, wgt,
                                                     hbf, resid, gates, selmk);

  hipMemsetAsync(ids1, 0, (size_t)NE*NTOK*4, stream);
  hipMemsetAsync(g2row, 0, (size_t)2*NE*NTOK*4, stream);
  hipMemsetAsync(g2tok, 0, (size_t)2*NE*NTOK*4, stream);

  builder_count<<<dim3(NTOK/256), 256, 0, stream>>>(selmk, bc1, bc2);
  builder_scan<<<dim3(1), 256, 0, stream>>>(bc1, bc2, meta, nch, TPC);
  builder_fill<<<dim3(NTOK/256), 256, 0, stream>>>(selmk, meta, ids1, g2row, g2tok, CH);

  for (int c = 0; c < nch; ++c) {
    // EPI0: 8-phase 256^2, gathered A, gelu->bf16 t1
    gemm8p<1><<<dim3(HD/256, CH/256, NE), 512, 0, stream>>>(
        hbf, w1t, ids1 + (size_t)c*8*CH,
        meta+MT_P1+c*8, meta+MT_OFF1+c*8,
        b1, nullptr, t1, HD, DM, CH);
    // EPI1: proven 128^2, slot-split scatter
    for (int s = 0; s < 2; ++s) {
      gemm_sparse<1><<<dim3(DM/128, CH/128, NE), 256, 0, stream>>>(
          t1, w2t, g2row + (size_t)(c*2+s)*8*CH, g2tok + (size_t)(c*2+s)*8*CH,
          meta+MT_PCNT2+c*16+s*8, meta+MT_CNT2+c*16+s*8, nullptr,
          b2, gates, nullptr, resid, HD, DM, CH);
    }
  }

  final_kernel<<<dim3(NTOK), 64, 0, stream>>>(resid, g_moe, beta_mo, g_out, beta_ou,
                                              w_cls, b_cls, out);
}